// Round 14
// baseline (229.425 us; speedup 1.0000x reference)
//
#include <hip/hip_runtime.h>
#include <hip/hip_bf16.h>

typedef short s16x8 __attribute__((ext_vector_type(8)));
typedef short s16x4 __attribute__((ext_vector_type(4)));
typedef float f32x4 __attribute__((ext_vector_type(4)));
typedef unsigned u32x4 __attribute__((ext_vector_type(4)));
typedef unsigned u32x2 __attribute__((ext_vector_type(2)));

#define N_ROWS 10000
#define MP   10048   // padded adj dim (157*64)
#define MPAD 10112   // partial-buffer row stride (79*128)

#if defined(__has_builtin)
#if __has_builtin(__builtin_amdgcn_cvt_pk_fp8_f32)
#define HAS_CVT_FP8 1
#endif
#endif
#ifndef HAS_CVT_FP8
#define HAS_CVT_FP8 0
#endif

// native RNE f32->bf16
__device__ inline short f2bf(float f) {
    __hip_bfloat16 h = __float2bfloat16(f);
    return __builtin_bit_cast(short, h);
}
__device__ inline float bf2f(short b) {
    return __builtin_bit_cast(float, ((unsigned)(unsigned short)b) << 16);
}

// manual f32 -> e4m3 (RNE), valid for x in [0,1]; flushes x < 2^-6 to 0
__device__ inline unsigned enc1(float x) {
    unsigned u = __builtin_bit_cast(unsigned, x);
    unsigned r = u + 0x7FFFFu + ((u >> 20) & 1u);
    unsigned byte = (((r >> 23) - 120u) << 3) | ((r >> 20) & 7u);
    return (u < 0x3C800000u) ? 0u : byte;
}
// decode two e4m3 bytes (non-negative) -> packed bf16 pair; E=0 -> 0
__device__ inline unsigned dec2(unsigned b0, unsigned b1) {
    unsigned r0 = (b0 + 960u) << 4; r0 = (b0 < 8u) ? 0u : r0;
    unsigned r1 = (b1 + 960u) << 4; r1 = (b1 < 8u) ? 0u : r1;
    return r0 | (r1 << 16);
}

// swizzled LDS index (units: bf16 elements, rows of 64)
__device__ inline int swz(int row, int col) {
    return (row * 64 + col) ^ ((row & 7) << 3);
}

// ---------------------------------------------------------------------------
// Unified MFMA GEMM, register prefetch depth PFD (1 or 2; round-3 parity scheme).
//  C[M x BN] = A[M x K] * B[K x BN]
//  AMODE 0: A f32 row-major (converted to bf16 on the fly)
//  AMODE 1: A bf16 row-major
//  AMODE 2: A fp8-e4m3 row-major (BM==128 only), decoded to bf16 in staging
//  AMODE 4: A = relu(sum_{s<8} Psrc[s] + bias) computed in staging (BM==64)
//  B: TRANSPOSED as Bt[BN][ldBt] bf16 (row n = column n of B)
//  CONV8 (AMODE 0): also emit staged A tile as fp8 to Af8out[MP-ld], row<MP
//  K-split: blockIdx.y picks [y*ktPerSplit, min(+ktPerSplit, Ktiles))
//  EPI 0: store C^T bf16 -> Cp[gc*ldC + gm]
//  EPI 1: store relu(C + bias) bf16 row-major -> Cp[gm*ldC + gc]
//  EPI 2: logits = C + bias; row log_softmax; store f32, gc<40
//  EPI 3: store bf16 partial -> ((short*)Cp + y*ldC*BN)[gm*BN + gc]
// ---------------------------------------------------------------------------
template<int BM, int BN, int WM, int WN, int AMODE, int EPI, int CONV8, int PFD>
__global__ __launch_bounds__(512)
void gemm_k(const void* __restrict__ Ap, int ldA, int Mval, int Kval,
            const short* __restrict__ Bt, int ldBt, int Ktiles,
            void* __restrict__ Cp, int ldC, int Cval,
            const float* __restrict__ bias, int ktPerSplit,
            unsigned char* __restrict__ Af8out,
            const short* __restrict__ Psrc)
{
    constexpr int WTM = BM / WM, WTN = BN / WN;
    constexpr int M_rep = WTM / 16, N_rep = WTN / 16;
    constexpr int AREP = (AMODE == 2) ? 1 : BM / 64, BREP = BN / 64;

    __shared__ alignas(16) short Alds[BM * 64];
    __shared__ alignas(16) short Blds[BN * 64];

    const int tid  = threadIdx.x;
    const int lane = tid & 63;
    const int w    = tid >> 6;
    const int wr   = w / WN, wc = w % WN;
    const int m0   = blockIdx.x * BM;

    // dual register sets (B set only live when PFD==2; else DCE'd)
    float4 va0A[AREP], va1A[AREP], va0B[AREP], va1B[AREP];
    s16x8  vabA[AREP], vabB[AREP];
    u32x4  v8A, v8B;
    s16x8  vbA[BREP], vbB[BREP];

    auto load_regs = [&](int kt, float4 (&va0)[AREP], float4 (&va1)[AREP],
                         s16x8 (&vab)[AREP], u32x4& v8, s16x8 (&vb)[BREP]) {
        const int k0 = kt * 64;
        if constexpr (AMODE == 2) {
            int row = tid >> 2, cc = (tid & 3) * 16;   // BM==128
            int gm  = m0 + row;
            u32x4 z = {0u, 0u, 0u, 0u};
            v8 = z;
            if (gm < Mval)
                v8 = *(const u32x4*)((const unsigned char*)Ap + (size_t)gm * ldA + k0 + cc);
        } else if constexpr (AMODE == 4) {
            // fused: A = relu(sum_8 Psrc + bias) (BM==64, AREP==1)
            int row = tid >> 3, cc = (tid & 7) * 8;
            int gm  = m0 + row;
            float s[8] = {0,0,0,0,0,0,0,0};
            if (gm < N_ROWS) {
                #pragma unroll
                for (int sp = 0; sp < 8; ++sp) {
                    s16x8 v = *(const s16x8*)(Psrc + (size_t)sp * MPAD * 256
                                              + (size_t)gm * 256 + k0 + cc);
                    #pragma unroll
                    for (int j = 0; j < 8; ++j) s[j] += bf2f(v[j]);
                }
                #pragma unroll
                for (int j = 0; j < 8; ++j)
                    vab[0][j] = f2bf(fmaxf(s[j] + bias[k0 + cc + j], 0.f));
            } else {
                #pragma unroll
                for (int j = 0; j < 8; ++j) vab[0][j] = 0;
            }
        } else {
            #pragma unroll
            for (int rep = 0; rep < AREP; ++rep) {
                int e   = tid + rep * 512;
                int row = e >> 3, cc = (e & 7) * 8;
                int gm  = m0 + row, gk = k0 + cc;
                if constexpr (AMODE == 0) {
                    float4 z = {0.f, 0.f, 0.f, 0.f};
                    va0[rep] = z; va1[rep] = z;
                    if (gm < Mval && gk < Kval) {
                        const float* p = (const float*)Ap + (long)gm * ldA + gk;
                        va0[rep] = *(const float4*)p;
                        va1[rep] = *(const float4*)(p + 4);
                    }
                } else {
                    if (gm < Mval && gk < Kval) {
                        vab[rep] = *(const s16x8*)((const short*)Ap + (long)gm * ldA + gk);
                    } else {
                        s16x8 z;
                        #pragma unroll
                        for (int j = 0; j < 8; ++j) z[j] = 0;
                        vab[rep] = z;
                    }
                }
            }
        }
        #pragma unroll
        for (int rep = 0; rep < BREP; ++rep) {
            int e   = tid + rep * 512;
            int row = e >> 3, cc = (e & 7) * 8;
            vb[rep] = *(const s16x8*)(Bt + (long)row * ldBt + k0 + cc);
        }
    };

    auto write_lds = [&](int kt, float4 (&va0)[AREP], float4 (&va1)[AREP],
                         s16x8 (&vab)[AREP], u32x4& v8, s16x8 (&vb)[BREP]) {
        const int k0 = kt * 64;
        if constexpr (AMODE == 2) {
            int row = tid >> 2, cc = (tid & 3) * 16;
            unsigned vv[4] = {v8[0], v8[1], v8[2], v8[3]};
            unsigned q[8];
            #pragma unroll
            for (int i = 0; i < 4; ++i) {
                q[2*i]   = dec2(vv[i] & 0xffu, (vv[i] >> 8) & 0xffu);
                q[2*i+1] = dec2((vv[i] >> 16) & 0xffu, (vv[i] >> 24) & 0xffu);
            }
            u32x4 lo = {q[0], q[1], q[2], q[3]};
            u32x4 hi = {q[4], q[5], q[6], q[7]};
            *(u32x4*)(&Alds[swz(row, cc)])     = lo;
            *(u32x4*)(&Alds[swz(row, cc + 8)]) = hi;
        } else {
            #pragma unroll
            for (int rep = 0; rep < AREP; ++rep) {
                int e   = tid + rep * 512;
                int row = e >> 3, cc = (e & 7) * 8;
                s16x8 b;
                if constexpr (AMODE == 0) {
                    b[0]=f2bf(va0[rep].x); b[1]=f2bf(va0[rep].y);
                    b[2]=f2bf(va0[rep].z); b[3]=f2bf(va0[rep].w);
                    b[4]=f2bf(va1[rep].x); b[5]=f2bf(va1[rep].y);
                    b[6]=f2bf(va1[rep].z); b[7]=f2bf(va1[rep].w);
                } else {
                    b = vab[rep];
                }
                *(s16x8*)(&Alds[swz(row, cc)]) = b;
                if constexpr (CONV8) {
                    if (m0 + row < MP) {
                        unsigned a8, b8;
#if HAS_CVT_FP8
                        a8 = (unsigned)__builtin_amdgcn_cvt_pk_fp8_f32(va0[rep].x, va0[rep].y, 0, false);
                        a8 = (unsigned)__builtin_amdgcn_cvt_pk_fp8_f32(va0[rep].z, va0[rep].w, (int)a8, true);
                        b8 = (unsigned)__builtin_amdgcn_cvt_pk_fp8_f32(va1[rep].x, va1[rep].y, 0, false);
                        b8 = (unsigned)__builtin_amdgcn_cvt_pk_fp8_f32(va1[rep].z, va1[rep].w, (int)b8, true);
#else
                        a8 = enc1(va0[rep].x) | (enc1(va0[rep].y) << 8)
                           | (enc1(va0[rep].z) << 16) | (enc1(va0[rep].w) << 24);
                        b8 = enc1(va1[rep].x) | (enc1(va1[rep].y) << 8)
                           | (enc1(va1[rep].z) << 16) | (enc1(va1[rep].w) << 24);
#endif
                        u32x2 st = {a8, b8};
                        *(u32x2*)(Af8out + (size_t)(m0 + row) * MP + (k0 + cc)) = st;
                    }
                }
            }
        }
        #pragma unroll
        for (int rep = 0; rep < BREP; ++rep) {
            int e   = tid + rep * 512;
            int row = e >> 3, cc = (e & 7) * 8;
            *(s16x8*)(&Blds[swz(row, cc)]) = vb[rep];
        }
    };

    f32x4 acc[M_rep][N_rep];
    const f32x4 zero4 = {0.f, 0.f, 0.f, 0.f};
    #pragma unroll
    for (int mi = 0; mi < M_rep; ++mi)
        #pragma unroll
        for (int nj = 0; nj < N_rep; ++nj) acc[mi][nj] = zero4;

    auto compute = [&]() {
        #pragma unroll
        for (int kk = 0; kk < 2; ++kk) {
            const int krd = kk * 32 + (lane >> 4) * 8;
            s16x8 af[M_rep], bf[N_rep];
            #pragma unroll
            for (int mi = 0; mi < M_rep; ++mi) {
                int row = wr * WTM + mi * 16 + (lane & 15);
                af[mi] = *(const s16x8*)(&Alds[swz(row, krd)]);
            }
            #pragma unroll
            for (int nj = 0; nj < N_rep; ++nj) {
                int row = wc * WTN + nj * 16 + (lane & 15);
                bf[nj] = *(const s16x8*)(&Blds[swz(row, krd)]);
            }
            #pragma unroll
            for (int mi = 0; mi < M_rep; ++mi)
                #pragma unroll
                for (int nj = 0; nj < N_rep; ++nj)
                    acc[mi][nj] = __builtin_amdgcn_mfma_f32_16x16x32_bf16(
                        af[mi], bf[nj], acc[mi][nj], 0, 0, 0);
        }
    };

    const int kt0 = blockIdx.y * ktPerSplit;
    int ktEnd = kt0 + ktPerSplit;
    if (ktEnd > Ktiles) ktEnd = Ktiles;

    if constexpr (PFD == 1) {
        load_regs(kt0, va0A, va1A, vabA, v8A, vbA);
        write_lds(kt0, va0A, va1A, vabA, v8A, vbA);
        for (int kt = kt0; kt < ktEnd; ++kt) {
            __syncthreads();
            if (kt + 1 < ktEnd) load_regs(kt + 1, va0A, va1A, vabA, v8A, vbA);
            compute();
            __syncthreads();
            if (kt + 1 < ktEnd) write_lds(kt + 1, va0A, va1A, vabA, v8A, vbA);
        }
    } else {
        // depth-2: loads for kt+2 issued at iter kt, written at iter kt+1
        load_regs(kt0, va0A, va1A, vabA, v8A, vbA);
        write_lds(kt0, va0A, va1A, vabA, v8A, vbA);
        if (kt0 + 1 < ktEnd) load_regs(kt0 + 1, va0B, va1B, vabB, v8B, vbB);
        for (int kt = kt0; kt < ktEnd; ++kt) {
            const bool even = ((kt - kt0) & 1) == 0;
            __syncthreads();
            if (kt + 2 < ktEnd) {
                if (even) load_regs(kt + 2, va0A, va1A, vabA, v8A, vbA);
                else      load_regs(kt + 2, va0B, va1B, vabB, v8B, vbB);
            }
            compute();
            __syncthreads();
            if (kt + 1 < ktEnd) {
                if (even) write_lds(kt + 1, va0B, va1B, vabB, v8B, vbB);
                else      write_lds(kt + 1, va0A, va1A, vabA, v8A, vbA);
            }
        }
    }

    // ---- epilogue ----
    const int mbase = m0 + wr * WTM;
    if constexpr (EPI == 0) {
        short* CT = (short*)Cp;
        #pragma unroll
        for (int mi = 0; mi < M_rep; ++mi) {
            int gm = mbase + mi * 16 + (lane >> 4) * 4;
            if (gm >= Cval) continue;
            #pragma unroll
            for (int nj = 0; nj < N_rep; ++nj) {
                int gc = wc * WTN + nj * 16 + (lane & 15);
                s16x4 p;
                #pragma unroll
                for (int r = 0; r < 4; ++r) p[r] = f2bf(acc[mi][nj][r]);
                *(s16x4*)(CT + (long)gc * ldC + gm) = p;
            }
        }
    } else if constexpr (EPI == 1) {
        short* C = (short*)Cp;
        #pragma unroll
        for (int nj = 0; nj < N_rep; ++nj) {
            int gc = wc * WTN + nj * 16 + (lane & 15);
            float b = bias[gc];
            #pragma unroll
            for (int mi = 0; mi < M_rep; ++mi) {
                int gm = mbase + mi * 16 + (lane >> 4) * 4;
                #pragma unroll
                for (int r = 0; r < 4; ++r) {
                    float v = acc[mi][nj][r] + b;
                    v = fmaxf(v, 0.f);
                    C[(long)(gm + r) * ldC + gc] = f2bf(v);
                }
            }
        }
    } else if constexpr (EPI == 2) {
        float* out = (float*)Cp;
        const int gmb = mbase + (lane >> 4) * 4;
        #pragma unroll
        for (int r = 0; r < 4; ++r) {
            float v[4];
            float mx = -__builtin_inff();
            #pragma unroll
            for (int nj = 0; nj < 4; ++nj) {
                int gc = nj * 16 + (lane & 15);
                float vv = -__builtin_inff();
                if (gc < 40) vv = acc[0][nj][r] + bias[gc];
                v[nj] = vv;
                mx = fmaxf(mx, vv);
            }
            #pragma unroll
            for (int off = 1; off < 16; off <<= 1)
                mx = fmaxf(mx, __shfl_xor(mx, off));
            float s = 0.f;
            #pragma unroll
            for (int nj = 0; nj < 4; ++nj)
                s += (v[nj] == -__builtin_inff()) ? 0.f : __expf(v[nj] - mx);
            #pragma unroll
            for (int off = 1; off < 16; off <<= 1)
                s += __shfl_xor(s, off);
            float lse = mx + __logf(s);
            int gm = gmb + r;
            if (gm < Cval) {
                #pragma unroll
                for (int nj = 0; nj < 4; ++nj) {
                    int gc = nj * 16 + (lane & 15);
                    if (gc < 40) out[(long)gm * ldC + gc] = v[nj] - lse;
                }
            }
        }
    } else {
        // EPI == 3: bf16 partial store; ldC = partial row stride (MPAD)
        short* Cpart = (short*)Cp + (size_t)blockIdx.y * ldC * BN;
        #pragma unroll
        for (int nj = 0; nj < N_rep; ++nj) {
            int gc = wc * WTN + nj * 16 + (lane & 15);
            #pragma unroll
            for (int mi = 0; mi < M_rep; ++mi) {
                int gm = mbase + mi * 16 + (lane >> 4) * 4;
                #pragma unroll
                for (int r = 0; r < 4; ++r)
                    Cpart[(long)(gm + r) * BN + gc] = f2bf(acc[mi][nj][r]);
            }
        }
    }
}

// H = relu(sum_s P[s] + b1), bf16 [MP][256] (fallback paths only)
__global__ __launch_bounds__(256)
void reduce_relu(const short* __restrict__ P, const float* __restrict__ b1,
                 short* __restrict__ H, int KS)
{
    int idx8 = blockIdx.x * 256 + threadIdx.x;
    int row  = idx8 >> 5;
    int col  = (idx8 & 31) * 8;
    s16x8 o;
    if (row < N_ROWS) {
        float s[8] = {0,0,0,0,0,0,0,0};
        for (int k = 0; k < KS; ++k) {
            s16x8 v = *(const s16x8*)(P + (size_t)k * MPAD * 256 + (size_t)row * 256 + col);
            #pragma unroll
            for (int j = 0; j < 8; ++j) s[j] += bf2f(v[j]);
        }
        #pragma unroll
        for (int j = 0; j < 8; ++j)
            o[j] = f2bf(fmaxf(s[j] + b1[col + j], 0.f));
    } else {
        #pragma unroll
        for (int j = 0; j < 8; ++j) o[j] = 0;
    }
    *(s16x8*)(H + (size_t)row * 256 + col) = o;
}

// out = log_softmax(sum_s P[s] + b2) over 40 cols; P rows 64 wide (bf16)
__global__ __launch_bounds__(256)
void reduce_softmax(const short* __restrict__ P, const float* __restrict__ b2,
                    float* __restrict__ out, int KS)
{
    int lane = threadIdx.x & 63;
    int row  = blockIdx.x * 4 + (threadIdx.x >> 6);
    if (row >= N_ROWS) return;
    float v = 0.f;
    if (KS == 32) {
        #pragma unroll
        for (int k = 0; k < 32; ++k)
            v += bf2f(P[(size_t)k * MPAD * 64 + (size_t)row * 64 + lane]);
    } else if (KS == 16) {
        #pragma unroll
        for (int k = 0; k < 16; ++k)
            v += bf2f(P[(size_t)k * MPAD * 64 + (size_t)row * 64 + lane]);
    } else {
        for (int k = 0; k < KS; ++k)
            v += bf2f(P[(size_t)k * MPAD * 64 + (size_t)row * 64 + lane]);
    }
    float vv = (lane < 40) ? v + b2[lane] : -__builtin_inff();
    float mx = vv;
    #pragma unroll
    for (int off = 1; off < 64; off <<= 1)
        mx = fmaxf(mx, __shfl_xor(mx, off));
    float e = (lane < 40) ? __expf(vv - mx) : 0.f;
    float s = e;
    #pragma unroll
    for (int off = 1; off < 64; off <<= 1)
        s += __shfl_xor(s, off);
    float lse = mx + __logf(s);
    if (lane < 40) out[(size_t)row * 40 + lane] = vv - lse;
}

// merged weight prep
__global__ __launch_bounds__(256)
void prep_w(const float* __restrict__ W1, const float* __restrict__ W2,
            short* __restrict__ W1t, short* __restrict__ W2t)
{
    int bid = blockIdx.x, c = threadIdx.x;
    if (bid < 512) {
        W1t[c * 512 + bid] = f2bf(W1[bid * 256 + c]);
    } else {
        int k = bid - 512;
        if (c < 64) {
            float v = (c < 40) ? W2[k * 40 + c] : 0.f;
            W2t[c * 256 + k] = f2bf(v);
        }
    }
}

extern "C" void kernel_launch(void* const* d_in, const int* in_sizes, int n_in,
                              void* d_out, int out_size, void* d_ws, size_t ws_size,
                              hipStream_t stream)
{
    const float* feature = (const float*)d_in[0];  // [10000,512]
    const float* adj     = (const float*)d_in[1];  // [10000,10000]
    const float* W1      = (const float*)d_in[2];  // [512,256]
    const float* b1      = (const float*)d_in[3];  // [256]
    const float* W2      = (const float*)d_in[4];  // [256,40]
    const float* b2      = (const float*)d_in[5];  // [40]
    float* out = (float*)d_out;                    // [10000,40]

    char* w = (char*)d_ws;
    short* XWt = (short*)w;  w += 256L * MP * 2;      // [256][10048] bf16
    short* H   = (short*)w;  w += (long)MP * 256 * 2; // [10048][256] bf16 (fallback)
    short* HWt = (short*)w;  w += 64L * MP * 2;       // [64][10048] bf16
    short* W1t = (short*)w;  w += 256L * 512 * 2;     // [256][512] bf16
    short* W2t = (short*)w;  w += 64L * 256 * 2;      // [64][256] bf16
    char*  base_noF8 = w;                             // fallback P location
    unsigned char* adjF8 = (unsigned char*)w;  w += (size_t)MP * MP; // 101 MB fp8
    short* P   = (short*)w;                           // bf16 K-split partials
    size_t offFull = (size_t)((char*)P - (char*)d_ws);
    size_t offNo   = (size_t)(base_noF8 - (char*)d_ws);

    const size_t p2 = (size_t)MPAD * 256 * 2;   // one G2 partial buffer
    const size_t p4 = (size_t)MPAD * 64 * 2;    // one G4 partial buffer
    const size_t pmax = (8 * p2 > 32 * p4) ? 8 * p2 : 32 * p4;  // equal, in fact

    prep_w<<<768, 256, 0, stream>>>(W1, W2, W1t, W2t);

    // G1: XW = feature @ W1 -> XWt (transposed store)
    gemm_k<64, 256, 2, 4, 0, 0, 0, 1><<<157, 512, 0, stream>>>(
        feature, 512, N_ROWS, 512, W1t, 512, 8, XWt, MP, MP, nullptr, 8, nullptr, nullptr);

    if (ws_size >= offFull + pmax) {
        // G2: bf16 partials = adj @ XW, KS=8; emits fp8 adj image (round-9 config)
        gemm_k<64, 256, 2, 4, 0, 3, 1, 1><<<dim3(157, 8), 512, 0, stream>>>(
            adj, N_ROWS, N_ROWS, N_ROWS, XWt, MP, 157, P, MPAD, MP, nullptr, 20, adjF8, nullptr);
        // G3: HW = relu(sumP + b1) @ W2 -> HWt (R1 fused into A-staging)
        gemm_k<64, 64, 4, 2, 4, 0, 0, 1><<<157, 512, 0, stream>>>(
            nullptr, 0, 0, 0, W2t, 256, 4, HWt, MP, MP, b1, 4, nullptr, P);
        // G4: bf16 partials = adjF8 @ HW, KS=32, BM=128, depth-2 prefetch
        gemm_k<128, 64, 4, 2, 2, 3, 0, 2><<<dim3(79, 32), 512, 0, stream>>>(
            adjF8, MP, MP, MP, HWt, MP, 157, P, MPAD, MP, nullptr, 5, nullptr, nullptr);
        // R2: out = log_softmax(sum + b2)
        reduce_softmax<<<2500, 256, 0, stream>>>(P, b2, out, 32);
    } else if (ws_size >= offNo + pmax) {
        // no-fp8 fallback: G4 re-reads f32 adj
        short* P0 = (short*)base_noF8;
        gemm_k<64, 256, 2, 4, 0, 3, 0, 1><<<dim3(157, 8), 512, 0, stream>>>(
            adj, N_ROWS, N_ROWS, N_ROWS, XWt, MP, 157, P0, MPAD, MP, nullptr, 20, nullptr, nullptr);
        gemm_k<64, 64, 4, 2, 4, 0, 0, 1><<<157, 512, 0, stream>>>(
            nullptr, 0, 0, 0, W2t, 256, 4, HWt, MP, MP, b1, 4, nullptr, P0);
        gemm_k<128, 64, 4, 2, 0, 3, 0, 1><<<dim3(79, 16), 512, 0, stream>>>(
            adj, N_ROWS, N_ROWS, N_ROWS, HWt, MP, 157, P0, MPAD, MP, nullptr, 10, nullptr, nullptr);
        reduce_softmax<<<2500, 256, 0, stream>>>(P0, b2, out, 16);
    } else if (ws_size >= offNo + 4 * p2) {
        // reduced split fallback (KS=4 both, separate R1)
        short* P0 = (short*)base_noF8;
        gemm_k<64, 256, 2, 4, 0, 3, 0, 1><<<dim3(157, 4), 512, 0, stream>>>(
            adj, N_ROWS, N_ROWS, N_ROWS, XWt, MP, 157, P0, MPAD, MP, nullptr, 40, nullptr, nullptr);
        reduce_relu<<<MP / 8, 256, 0, stream>>>(P0, b1, H, 4);
        gemm_k<64, 64, 4, 2, 1, 0, 0, 1><<<157, 512, 0, stream>>>(
            H, 256, MP, 256, W2t, 256, 4, HWt, MP, MP, nullptr, 4, nullptr, nullptr);
        gemm_k<128, 64, 4, 2, 0, 3, 0, 1><<<dim3(79, 4), 512, 0, stream>>>(
            adj, N_ROWS, N_ROWS, N_ROWS, HWt, MP, 157, P0, MPAD, MP, nullptr, 40, nullptr, nullptr);
        reduce_softmax<<<2500, 256, 0, stream>>>(P0, b2, out, 4);
    } else {
        // fully fused fallback (no split)
        gemm_k<64, 256, 2, 4, 0, 1, 0, 1><<<157, 512, 0, stream>>>(
            adj, N_ROWS, N_ROWS, N_ROWS, XWt, MP, 157, H, 256, MP, b1, 157, nullptr, nullptr);
        gemm_k<64, 64, 4, 2, 1, 0, 0, 1><<<157, 512, 0, stream>>>(
            H, 256, MP, 256, W2t, 256, 4, HWt, MP, MP, nullptr, 4, nullptr, nullptr);
        gemm_k<128, 64, 8, 1, 0, 2, 0, 1><<<79, 512, 0, stream>>>(
            adj, N_ROWS, N_ROWS, N_ROWS, HWt, MP, 157, out, 40, N_ROWS, b2, 157, nullptr, nullptr);
    }
}

// Round 15
// 221.475 us; speedup vs baseline: 1.0359x; 1.0359x over previous
//
#include <hip/hip_runtime.h>
#include <hip/hip_bf16.h>
#include <hip/hip_fp16.h>

typedef short s16x8 __attribute__((ext_vector_type(8)));
typedef short s16x4 __attribute__((ext_vector_type(4)));
typedef float f32x4 __attribute__((ext_vector_type(4)));
typedef _Float16 f16x8 __attribute__((ext_vector_type(8)));
typedef unsigned u32x4 __attribute__((ext_vector_type(4)));
typedef unsigned u32x2 __attribute__((ext_vector_type(2)));

#define N_ROWS 10000
#define MP   10048   // padded adj dim (157*64)
#define MPAD 10112   // partial-buffer row stride (79*128)

#if defined(__has_builtin)
#if __has_builtin(__builtin_amdgcn_cvt_pk_bf8_f32)
#define HAS_CVT_BF8 1
#endif
#endif
#ifndef HAS_CVT_BF8
#define HAS_CVT_BF8 0
#endif

// native RNE f32->bf16
__device__ inline short f2bf(float f) {
    __hip_bfloat16 h = __float2bfloat16(f);
    return __builtin_bit_cast(short, h);
}
__device__ inline float bf2f(short b) {
    return __builtin_bit_cast(float, ((unsigned)(unsigned short)b) << 16);
}
// f32 -> f16 bits
__device__ inline short f2fh(float f) {
    __half h = __float2half(f);
    return __builtin_bit_cast(short, h);
}

// manual f32 -> e5m2 (via f16, RNE at the byte boundary); exact for 0
__device__ inline unsigned enc_bf8(float x) {
    unsigned short h = (unsigned short)__builtin_bit_cast(short, __float2half(x));
    unsigned r = ((unsigned)h + 0x7Fu + ((h >> 8) & 1u)) >> 8;
    return r & 0xffu;
}

// swizzled LDS index (units: 16-bit elements, rows of 64)
__device__ inline int swz(int row, int col) {
    return (row * 64 + col) ^ ((row & 7) << 3);
}

// ---------------------------------------------------------------------------
// Unified MFMA GEMM, depth-1 register prefetch (round-9/13 structure).
//  C[M x BN] = A[M x K] * B[K x BN]
//  AMODE 0: A f32 row-major (cvt to bf16 on the fly)
//  AMODE 1: A bf16 row-major
//  AMODE 2: A e5m2 row-major (BM==128 only); decode = byte<<8 -> f16;
//           compute uses f16 MFMA (B must then hold f16 bits: HWt via EPI 5)
//  AMODE 4: A = relu(sum_{s<8} Psrc[s] + bias) computed in staging (BM==64)
//  B: TRANSPOSED as Bt[BN][ldBt] 16-bit (bf16, or f16 for AMODE-2 consumers)
//  CONV8 (AMODE 0): also emit staged A tile as e5m2 to Af8out[MP-ld], row<MP
//  EPI 0: store C^T bf16 -> Cp[gc*ldC + gm]
//  EPI 5: store C^T f16  -> Cp[gc*ldC + gm]
//  EPI 2: logits = C + bias; row log_softmax; store f32, gc<40
//  EPI 3: store bf16 partial -> ((short*)Cp + y*ldC*BN)[gm*BN + gc]
// ---------------------------------------------------------------------------
template<int BM, int BN, int WM, int WN, int AMODE, int EPI, int CONV8>
__global__ __launch_bounds__(512)
void gemm_k(const void* __restrict__ Ap, int ldA, int Mval, int Kval,
            const short* __restrict__ Bt, int ldBt, int Ktiles,
            void* __restrict__ Cp, int ldC, int Cval,
            const float* __restrict__ bias, int ktPerSplit,
            unsigned char* __restrict__ Af8out,
            const short* __restrict__ Psrc)
{
    constexpr int WTM = BM / WM, WTN = BN / WN;
    constexpr int M_rep = WTM / 16, N_rep = WTN / 16;
    constexpr int AREP = (AMODE == 2) ? 1 : BM / 64, BREP = BN / 64;

    __shared__ alignas(16) short Alds[BM * 64];
    __shared__ alignas(16) short Blds[BN * 64];

    const int tid  = threadIdx.x;
    const int lane = tid & 63;
    const int w    = tid >> 6;
    const int wr   = w / WN, wc = w % WN;
    const int m0   = blockIdx.x * BM;

    float4 va0[AREP], va1[AREP];
    s16x8  vab[AREP];
    u32x4  v8;
    s16x8  vb[BREP];

    auto load_regs = [&](int kt) {
        const int k0 = kt * 64;
        if constexpr (AMODE == 2) {
            int row = tid >> 2, cc = (tid & 3) * 16;   // BM==128
            int gm  = m0 + row;
            u32x4 z = {0u, 0u, 0u, 0u};
            v8 = z;
            if (gm < Mval)
                v8 = *(const u32x4*)((const unsigned char*)Ap + (size_t)gm * ldA + k0 + cc);
        } else if constexpr (AMODE == 4) {
            // fused: A = relu(sum_8 Psrc + bias) (BM==64, AREP==1)
            int row = tid >> 3, cc = (tid & 7) * 8;
            int gm  = m0 + row;
            float s[8] = {0,0,0,0,0,0,0,0};
            if (gm < N_ROWS) {
                #pragma unroll
                for (int sp = 0; sp < 8; ++sp) {
                    s16x8 v = *(const s16x8*)(Psrc + (size_t)sp * MPAD * 256
                                              + (size_t)gm * 256 + k0 + cc);
                    #pragma unroll
                    for (int j = 0; j < 8; ++j) s[j] += bf2f(v[j]);
                }
                #pragma unroll
                for (int j = 0; j < 8; ++j)
                    vab[0][j] = f2bf(fmaxf(s[j] + bias[k0 + cc + j], 0.f));
            } else {
                #pragma unroll
                for (int j = 0; j < 8; ++j) vab[0][j] = 0;
            }
        } else {
            #pragma unroll
            for (int rep = 0; rep < AREP; ++rep) {
                int e   = tid + rep * 512;
                int row = e >> 3, cc = (e & 7) * 8;
                int gm  = m0 + row, gk = k0 + cc;
                if constexpr (AMODE == 0) {
                    float4 z = {0.f, 0.f, 0.f, 0.f};
                    va0[rep] = z; va1[rep] = z;
                    if (gm < Mval && gk < Kval) {
                        const float* p = (const float*)Ap + (long)gm * ldA + gk;
                        va0[rep] = *(const float4*)p;
                        va1[rep] = *(const float4*)(p + 4);
                    }
                } else {
                    if (gm < Mval && gk < Kval) {
                        vab[rep] = *(const s16x8*)((const short*)Ap + (long)gm * ldA + gk);
                    } else {
                        s16x8 z;
                        #pragma unroll
                        for (int j = 0; j < 8; ++j) z[j] = 0;
                        vab[rep] = z;
                    }
                }
            }
        }
        #pragma unroll
        for (int rep = 0; rep < BREP; ++rep) {
            int e   = tid + rep * 512;
            int row = e >> 3, cc = (e & 7) * 8;
            vb[rep] = *(const s16x8*)(Bt + (long)row * ldBt + k0 + cc);
        }
    };

    auto write_lds = [&](int kt) {
        const int k0 = kt * 64;
        if constexpr (AMODE == 2) {
            int row = tid >> 2, cc = (tid & 3) * 16;
            // e5m2 -> f16 is exactly byte<<8 (branchless; 0 and subnormals exact)
            unsigned q[8];
            #pragma unroll
            for (int i = 0; i < 4; ++i) {
                unsigned v = v8[i];
                q[2*i]   = ((v & 0x000000ffu) << 8) | ((v & 0x0000ff00u) << 16);
                q[2*i+1] = ((v & 0x00ff0000u) >> 8) | (v & 0xff000000u);
            }
            u32x4 lo = {q[0], q[1], q[2], q[3]};
            u32x4 hi = {q[4], q[5], q[6], q[7]};
            *(u32x4*)(&Alds[swz(row, cc)])     = lo;
            *(u32x4*)(&Alds[swz(row, cc + 8)]) = hi;
        } else {
            #pragma unroll
            for (int rep = 0; rep < AREP; ++rep) {
                int e   = tid + rep * 512;
                int row = e >> 3, cc = (e & 7) * 8;
                s16x8 b;
                if constexpr (AMODE == 0) {
                    b[0]=f2bf(va0[rep].x); b[1]=f2bf(va0[rep].y);
                    b[2]=f2bf(va0[rep].z); b[3]=f2bf(va0[rep].w);
                    b[4]=f2bf(va1[rep].x); b[5]=f2bf(va1[rep].y);
                    b[6]=f2bf(va1[rep].z); b[7]=f2bf(va1[rep].w);
                } else {
                    b = vab[rep];
                }
                *(s16x8*)(&Alds[swz(row, cc)]) = b;
                if constexpr (CONV8) {
                    if (m0 + row < MP) {
                        unsigned a8, b8;
#if HAS_CVT_BF8
                        a8 = (unsigned)__builtin_amdgcn_cvt_pk_bf8_f32(va0[rep].x, va0[rep].y, 0, false);
                        a8 = (unsigned)__builtin_amdgcn_cvt_pk_bf8_f32(va0[rep].z, va0[rep].w, (int)a8, true);
                        b8 = (unsigned)__builtin_amdgcn_cvt_pk_bf8_f32(va1[rep].x, va1[rep].y, 0, false);
                        b8 = (unsigned)__builtin_amdgcn_cvt_pk_bf8_f32(va1[rep].z, va1[rep].w, (int)b8, true);
#else
                        a8 = enc_bf8(va0[rep].x) | (enc_bf8(va0[rep].y) << 8)
                           | (enc_bf8(va0[rep].z) << 16) | (enc_bf8(va0[rep].w) << 24);
                        b8 = enc_bf8(va1[rep].x) | (enc_bf8(va1[rep].y) << 8)
                           | (enc_bf8(va1[rep].z) << 16) | (enc_bf8(va1[rep].w) << 24);
#endif
                        u32x2 st = {a8, b8};
                        *(u32x2*)(Af8out + (size_t)(m0 + row) * MP + (k0 + cc)) = st;
                    }
                }
            }
        }
        #pragma unroll
        for (int rep = 0; rep < BREP; ++rep) {
            int e   = tid + rep * 512;
            int row = e >> 3, cc = (e & 7) * 8;
            *(s16x8*)(&Blds[swz(row, cc)]) = vb[rep];
        }
    };

    f32x4 acc[M_rep][N_rep];
    const f32x4 zero4 = {0.f, 0.f, 0.f, 0.f};
    #pragma unroll
    for (int mi = 0; mi < M_rep; ++mi)
        #pragma unroll
        for (int nj = 0; nj < N_rep; ++nj) acc[mi][nj] = zero4;

    const int kt0 = blockIdx.y * ktPerSplit;
    int ktEnd = kt0 + ktPerSplit;
    if (ktEnd > Ktiles) ktEnd = Ktiles;

    load_regs(kt0);
    write_lds(kt0);

    for (int kt = kt0; kt < ktEnd; ++kt) {
        __syncthreads();
        if (kt + 1 < ktEnd) load_regs(kt + 1);
        #pragma unroll
        for (int kk = 0; kk < 2; ++kk) {
            const int krd = kk * 32 + (lane >> 4) * 8;
            s16x8 af[M_rep], bf[N_rep];
            #pragma unroll
            for (int mi = 0; mi < M_rep; ++mi) {
                int row = wr * WTM + mi * 16 + (lane & 15);
                af[mi] = *(const s16x8*)(&Alds[swz(row, krd)]);
            }
            #pragma unroll
            for (int nj = 0; nj < N_rep; ++nj) {
                int row = wc * WTN + nj * 16 + (lane & 15);
                bf[nj] = *(const s16x8*)(&Blds[swz(row, krd)]);
            }
            #pragma unroll
            for (int mi = 0; mi < M_rep; ++mi)
                #pragma unroll
                for (int nj = 0; nj < N_rep; ++nj) {
                    if constexpr (AMODE == 2) {
                        acc[mi][nj] = __builtin_amdgcn_mfma_f32_16x16x32_f16(
                            __builtin_bit_cast(f16x8, af[mi]),
                            __builtin_bit_cast(f16x8, bf[nj]),
                            acc[mi][nj], 0, 0, 0);
                    } else {
                        acc[mi][nj] = __builtin_amdgcn_mfma_f32_16x16x32_bf16(
                            af[mi], bf[nj], acc[mi][nj], 0, 0, 0);
                    }
                }
        }
        __syncthreads();
        if (kt + 1 < ktEnd) write_lds(kt + 1);
    }

    // ---- epilogue ----
    const int mbase = m0 + wr * WTM;
    if constexpr (EPI == 0 || EPI == 5) {
        short* CT = (short*)Cp;
        #pragma unroll
        for (int mi = 0; mi < M_rep; ++mi) {
            int gm = mbase + mi * 16 + (lane >> 4) * 4;
            if (gm >= Cval) continue;
            #pragma unroll
            for (int nj = 0; nj < N_rep; ++nj) {
                int gc = wc * WTN + nj * 16 + (lane & 15);
                s16x4 p;
                #pragma unroll
                for (int r = 0; r < 4; ++r)
                    p[r] = (EPI == 5) ? f2fh(acc[mi][nj][r]) : f2bf(acc[mi][nj][r]);
                *(s16x4*)(CT + (long)gc * ldC + gm) = p;
            }
        }
    } else if constexpr (EPI == 2) {
        float* out = (float*)Cp;
        const int gmb = mbase + (lane >> 4) * 4;
        #pragma unroll
        for (int r = 0; r < 4; ++r) {
            float v[4];
            float mx = -__builtin_inff();
            #pragma unroll
            for (int nj = 0; nj < 4; ++nj) {
                int gc = nj * 16 + (lane & 15);
                float vv = -__builtin_inff();
                if (gc < 40) vv = acc[0][nj][r] + bias[gc];
                v[nj] = vv;
                mx = fmaxf(mx, vv);
            }
            #pragma unroll
            for (int off = 1; off < 16; off <<= 1)
                mx = fmaxf(mx, __shfl_xor(mx, off));
            float s = 0.f;
            #pragma unroll
            for (int nj = 0; nj < 4; ++nj)
                s += (v[nj] == -__builtin_inff()) ? 0.f : __expf(v[nj] - mx);
            #pragma unroll
            for (int off = 1; off < 16; off <<= 1)
                s += __shfl_xor(s, off);
            float lse = mx + __logf(s);
            int gm = gmb + r;
            if (gm < Cval) {
                #pragma unroll
                for (int nj = 0; nj < 4; ++nj) {
                    int gc = nj * 16 + (lane & 15);
                    if (gc < 40) out[(long)gm * ldC + gc] = v[nj] - lse;
                }
            }
        }
    } else {
        // EPI == 3: bf16 partial store; ldC = partial row stride (MPAD)
        short* Cpart = (short*)Cp + (size_t)blockIdx.y * ldC * BN;
        #pragma unroll
        for (int nj = 0; nj < N_rep; ++nj) {
            int gc = wc * WTN + nj * 16 + (lane & 15);
            #pragma unroll
            for (int mi = 0; mi < M_rep; ++mi) {
                int gm = mbase + mi * 16 + (lane >> 4) * 4;
                #pragma unroll
                for (int r = 0; r < 4; ++r)
                    Cpart[(long)(gm + r) * BN + gc] = f2bf(acc[mi][nj][r]);
            }
        }
    }
}

// H = relu(sum_s P[s] + b1), bf16 [MP][256] (fallback paths only)
__global__ __launch_bounds__(256)
void reduce_relu(const short* __restrict__ P, const float* __restrict__ b1,
                 short* __restrict__ H, int KS)
{
    int idx8 = blockIdx.x * 256 + threadIdx.x;
    int row  = idx8 >> 5;
    int col  = (idx8 & 31) * 8;
    s16x8 o;
    if (row < N_ROWS) {
        float s[8] = {0,0,0,0,0,0,0,0};
        for (int k = 0; k < KS; ++k) {
            s16x8 v = *(const s16x8*)(P + (size_t)k * MPAD * 256 + (size_t)row * 256 + col);
            #pragma unroll
            for (int j = 0; j < 8; ++j) s[j] += bf2f(v[j]);
        }
        #pragma unroll
        for (int j = 0; j < 8; ++j)
            o[j] = f2bf(fmaxf(s[j] + b1[col + j], 0.f));
    } else {
        #pragma unroll
        for (int j = 0; j < 8; ++j) o[j] = 0;
    }
    *(s16x8*)(H + (size_t)row * 256 + col) = o;
}

// out = log_softmax(sum_s P[s] + b2) over 40 cols; P rows 64 wide (bf16)
__global__ __launch_bounds__(256)
void reduce_softmax(const short* __restrict__ P, const float* __restrict__ b2,
                    float* __restrict__ out, int KS)
{
    int lane = threadIdx.x & 63;
    int row  = blockIdx.x * 4 + (threadIdx.x >> 6);
    if (row >= N_ROWS) return;
    float v = 0.f;
    if (KS == 16) {
        #pragma unroll
        for (int k = 0; k < 16; ++k)
            v += bf2f(P[(size_t)k * MPAD * 64 + (size_t)row * 64 + lane]);
    } else {
        for (int k = 0; k < KS; ++k)
            v += bf2f(P[(size_t)k * MPAD * 64 + (size_t)row * 64 + lane]);
    }
    float vv = (lane < 40) ? v + b2[lane] : -__builtin_inff();
    float mx = vv;
    #pragma unroll
    for (int off = 1; off < 64; off <<= 1)
        mx = fmaxf(mx, __shfl_xor(mx, off));
    float e = (lane < 40) ? __expf(vv - mx) : 0.f;
    float s = e;
    #pragma unroll
    for (int off = 1; off < 64; off <<= 1)
        s += __shfl_xor(s, off);
    float lse = mx + __logf(s);
    if (lane < 40) out[(size_t)row * 40 + lane] = vv - lse;
}

// merged weight prep
__global__ __launch_bounds__(256)
void prep_w(const float* __restrict__ W1, const float* __restrict__ W2,
            short* __restrict__ W1t, short* __restrict__ W2t)
{
    int bid = blockIdx.x, c = threadIdx.x;
    if (bid < 512) {
        W1t[c * 512 + bid] = f2bf(W1[bid * 256 + c]);
    } else {
        int k = bid - 512;
        if (c < 64) {
            float v = (c < 40) ? W2[k * 40 + c] : 0.f;
            W2t[c * 256 + k] = f2bf(v);
        }
    }
}

extern "C" void kernel_launch(void* const* d_in, const int* in_sizes, int n_in,
                              void* d_out, int out_size, void* d_ws, size_t ws_size,
                              hipStream_t stream)
{
    const float* feature = (const float*)d_in[0];  // [10000,512]
    const float* adj     = (const float*)d_in[1];  // [10000,10000]
    const float* W1      = (const float*)d_in[2];  // [512,256]
    const float* b1      = (const float*)d_in[3];  // [256]
    const float* W2      = (const float*)d_in[4];  // [256,40]
    const float* b2      = (const float*)d_in[5];  // [40]
    float* out = (float*)d_out;                    // [10000,40]

    char* w = (char*)d_ws;
    short* XWt = (short*)w;  w += 256L * MP * 2;      // [256][10048] bf16
    short* H   = (short*)w;  w += (long)MP * 256 * 2; // [10048][256] bf16 (fallback)
    short* HWt = (short*)w;  w += 64L * MP * 2;       // [64][10048] 16-bit (f16 on full path)
    short* W1t = (short*)w;  w += 256L * 512 * 2;     // [256][512] bf16
    short* W2t = (short*)w;  w += 64L * 256 * 2;      // [64][256] bf16
    char*  base_noF8 = w;                             // fallback P location
    unsigned char* adjF8 = (unsigned char*)w;  w += (size_t)MP * MP; // 101 MB e5m2
    short* P   = (short*)w;                           // bf16 K-split partials
    size_t offFull = (size_t)((char*)P - (char*)d_ws);
    size_t offNo   = (size_t)(base_noF8 - (char*)d_ws);

    const size_t p2 = (size_t)MPAD * 256 * 2;   // one G2 partial buffer
    const size_t p4 = (size_t)MPAD * 64 * 2;    // one G4 partial buffer
    const size_t pmax = (8 * p2 > 16 * p4) ? 8 * p2 : 16 * p4;

    prep_w<<<768, 256, 0, stream>>>(W1, W2, W1t, W2t);

    // G1: XW = feature @ W1 -> XWt (transposed bf16 store)
    gemm_k<64, 256, 2, 4, 0, 0, 0><<<157, 512, 0, stream>>>(
        feature, 512, N_ROWS, 512, W1t, 512, 8, XWt, MP, MP, nullptr, 8, nullptr, nullptr);

    if (ws_size >= offFull + pmax) {
        // G2: bf16 partials = adj @ XW, KS=8; emits e5m2 adj image (round-9 config)
        gemm_k<64, 256, 2, 4, 0, 3, 1><<<dim3(157, 8), 512, 0, stream>>>(
            adj, N_ROWS, N_ROWS, N_ROWS, XWt, MP, 157, P, MPAD, MP, nullptr, 20, adjF8, nullptr);
        // G3: HW = relu(sumP + b1) @ W2 -> HWt as f16 (EPI 5; R1 fused into A-staging)
        gemm_k<64, 64, 4, 2, 4, 5, 0><<<157, 512, 0, stream>>>(
            nullptr, 0, 0, 0, W2t, 256, 4, HWt, MP, MP, b1, 4, nullptr, P);
        // G4: bf16 partials = adjF8(e5m2) @ HWt(f16), KS=16, BM=128, f16 MFMA
        gemm_k<128, 64, 4, 2, 2, 3, 0><<<dim3(79, 16), 512, 0, stream>>>(
            adjF8, MP, MP, MP, HWt, MP, 157, P, MPAD, MP, nullptr, 10, nullptr, nullptr);
        // R2: out = log_softmax(sum + b2)
        reduce_softmax<<<2500, 256, 0, stream>>>(P, b2, out, 16);
    } else if (ws_size >= offNo + pmax) {
        // no-fp8 fallback: G4 re-reads f32 adj (all-bf16 pipeline)
        short* P0 = (short*)base_noF8;
        gemm_k<64, 256, 2, 4, 0, 3, 0><<<dim3(157, 8), 512, 0, stream>>>(
            adj, N_ROWS, N_ROWS, N_ROWS, XWt, MP, 157, P0, MPAD, MP, nullptr, 20, nullptr, nullptr);
        gemm_k<64, 64, 4, 2, 4, 0, 0><<<157, 512, 0, stream>>>(
            nullptr, 0, 0, 0, W2t, 256, 4, HWt, MP, MP, b1, 4, nullptr, P0);
        gemm_k<128, 64, 4, 2, 0, 3, 0><<<dim3(79, 16), 512, 0, stream>>>(
            adj, N_ROWS, N_ROWS, N_ROWS, HWt, MP, 157, P0, MPAD, MP, nullptr, 10, nullptr, nullptr);
        reduce_softmax<<<2500, 256, 0, stream>>>(P0, b2, out, 16);
    } else if (ws_size >= offNo + 4 * p2) {
        // reduced split fallback (KS=4 both, separate R1)
        short* P0 = (short*)base_noF8;
        gemm_k<64, 256, 2, 4, 0, 3, 0><<<dim3(157, 4), 512, 0, stream>>>(
            adj, N_ROWS, N_ROWS, N_ROWS, XWt, MP, 157, P0, MPAD, MP, nullptr, 40, nullptr, nullptr);
        reduce_relu<<<MP / 8, 256, 0, stream>>>(P0, b1, H, 4);
        gemm_k<64, 64, 4, 2, 1, 0, 0><<<157, 512, 0, stream>>>(
            H, 256, MP, 256, W2t, 256, 4, HWt, MP, MP, nullptr, 4, nullptr, nullptr);
        gemm_k<128, 64, 4, 2, 0, 3, 0><<<dim3(79, 4), 512, 0, stream>>>(
            adj, N_ROWS, N_ROWS, N_ROWS, HWt, MP, 157, P0, MPAD, MP, nullptr, 40, nullptr, nullptr);
        reduce_softmax<<<2500, 256, 0, stream>>>(P0, b2, out, 4);
    } else {
        // fully fused fallback (no split)
        gemm_k<64, 256, 2, 4, 0, 1, 0><<<157, 512, 0, stream>>>(
            adj, N_ROWS, N_ROWS, N_ROWS, XWt, MP, 157, H, 256, MP, b1, 157, nullptr, nullptr);
        gemm_k<64, 64, 4, 2, 1, 0, 0><<<157, 512, 0, stream>>>(
            H, 256, MP, 256, W2t, 256, 4, HWt, MP, MP, nullptr, 4, nullptr, nullptr);
        gemm_k<128, 64, 8, 1, 0, 2, 0><<<79, 512, 0, stream>>>(
            adj, N_ROWS, N_ROWS, N_ROWS, HWt, MP, 157, out, 40, N_ROWS, b2, 157, nullptr, nullptr);
    }
}